// Round 1
// baseline (51.514 us; speedup 1.0000x reference)
//
#include <hip/hip_runtime.h>

#define N 1024
#define D 64
#define SPLIT 4
#define EPS 1e-12f
#define R2 16
#define ROWS 4

// K1: partial[m][c][s] = sum over i in [s*256,(s+1)*256), j in [0,N) of |z[m][i][c]-z[m][j][c]|
__global__ __launch_bounds__(256) void colsum_kernel(const float* __restrict__ z1,
                                                     const float* __restrict__ z2,
                                                     float* __restrict__ partial) {
    int b = blockIdx.x;
    int s = b & (SPLIT - 1);
    int c = (b / SPLIT) & (D - 1);
    int m = b / (SPLIT * D);
    const float* z = m ? z2 : z1;
    __shared__ alignas(16) float col[N];
    __shared__ float red[4];
    int tid = threadIdx.x;
    for (int i = tid; i < N; i += 256) col[i] = z[i * D + c];
    __syncthreads();
    float a = col[s * 256 + tid];
    float sum = 0.f;
    const float4* col4 = reinterpret_cast<const float4*>(col);
    #pragma unroll 4
    for (int j4 = 0; j4 < N / 4; ++j4) {
        float4 v = col4[j4];
        sum += fabsf(a - v.x) + fabsf(a - v.y) + fabsf(a - v.z) + fabsf(a - v.w);
    }
    #pragma unroll
    for (int off = 32; off; off >>= 1) sum += __shfl_down(sum, off, 64);
    int lane = tid & 63, wave = tid >> 6;
    if (lane == 0) red[wave] = sum;
    __syncthreads();
    if (tid == 0) partial[(m * D + c) * SPLIT + s] = red[0] + red[1] + red[2] + red[3];
}

// K2: p[m][i][c] = sum_k z[m][i][k] * W1[k][c] * invS[m][k]
__global__ __launch_bounds__(256) void proj_kernel(const float* __restrict__ z1,
                                                   const float* __restrict__ z2,
                                                   const float* __restrict__ W1,
                                                   const float* __restrict__ partial,
                                                   float* __restrict__ p) {
    int blocks_per_m = N / R2;  // 64
    int m = blockIdx.x / blocks_per_m;
    int rb = blockIdx.x % blocks_per_m;
    int i0 = rb * R2;
    const float* z = m ? z2 : z1;
    __shared__ float invS[D];
    __shared__ float sW[D * D];          // 16KB
    __shared__ float zs[R2][D];          // 4KB
    int tid = threadIdx.x;
    if (tid < D) {
        const float* pk = partial + (m * D + tid) * SPLIT;
        invS[tid] = 1.f / fmaxf(pk[0] + pk[1] + pk[2] + pk[3], EPS);
    }
    for (int idx = tid; idx < R2 * D; idx += 256) {
        zs[idx / D][idx % D] = z[(i0 + idx / D) * D + (idx % D)];
    }
    __syncthreads();
    for (int idx = tid; idx < D * D; idx += 256) {
        sW[idx] = W1[idx] * invS[idx / D];
    }
    __syncthreads();
    int c = tid & (D - 1);
    int rq = tid >> 6;  // 0..3
    float acc[4] = {0.f, 0.f, 0.f, 0.f};
    for (int k = 0; k < D; ++k) {
        float w = sW[k * D + c];
        #pragma unroll
        for (int q = 0; q < 4; ++q) acc[q] += zs[rq + 4 * q][k] * w;
    }
    #pragma unroll
    for (int q = 0; q < 4; ++q) p[(size_t)(m * N + i0 + rq + 4 * q) * D + c] = acc[q];
}

// K3: o[i,j] = relu(sum_c relu(p[i,c]+b1[c]-p[j,c]) * W2[c] + b2); row-L1-normalize; write planes m and m+2
__global__ __launch_bounds__(256) void pair_kernel(const float* __restrict__ p,
                                                   const float* __restrict__ b1,
                                                   const float* __restrict__ W2,
                                                   const float* __restrict__ b2,
                                                   float* __restrict__ out) {
    int blocks_per_m = N / ROWS;  // 256
    int m = blockIdx.x / blocks_per_m;
    int rb = blockIdx.x % blocks_per_m;
    int i0 = rb * ROWS;
    const float* pm = p + (size_t)m * N * D;
    __shared__ alignas(16) float vi[ROWS][D];
    __shared__ alignas(16) float w2s[D];
    __shared__ alignas(16) float obuf[ROWS][N];  // 16KB
    __shared__ float red[ROWS][4];
    int tid = threadIdx.x;
    if (tid < D) w2s[tid] = W2[tid];
    for (int idx = tid; idx < ROWS * D; idx += 256) {
        int r = idx / D, c = idx % D;
        vi[r][c] = pm[(size_t)(i0 + r) * D + c] + b1[c];
    }
    __syncthreads();
    float b2v = b2[0];
    for (int jt = 0; jt < N / 256; ++jt) {
        int j = jt * 256 + tid;
        const float4* pj = reinterpret_cast<const float4*>(pm + (size_t)j * D);
        float4 uj[16];
        #pragma unroll
        for (int q = 0; q < 16; ++q) uj[q] = pj[q];
        #pragma unroll
        for (int r = 0; r < ROWS; ++r) {
            const float4* vr = reinterpret_cast<const float4*>(&vi[r][0]);
            const float4* w4 = reinterpret_cast<const float4*>(&w2s[0]);
            float acc = 0.f;
            #pragma unroll
            for (int q = 0; q < 16; ++q) {
                float4 a = vr[q], w = w4[q], u = uj[q];
                acc += fmaxf(a.x - u.x, 0.f) * w.x;
                acc += fmaxf(a.y - u.y, 0.f) * w.y;
                acc += fmaxf(a.z - u.z, 0.f) * w.z;
                acc += fmaxf(a.w - u.w, 0.f) * w.w;
            }
            obuf[r][j] = fmaxf(acc + b2v, 0.f);
        }
    }
    __syncthreads();
    int lane = tid & 63, wave = tid >> 6;
    #pragma unroll
    for (int r = 0; r < ROWS; ++r) {
        float s = 0.f;
        #pragma unroll
        for (int jt = 0; jt < N / 256; ++jt) s += obuf[r][jt * 256 + tid];
        #pragma unroll
        for (int off = 32; off; off >>= 1) s += __shfl_down(s, off, 64);
        if (lane == 0) red[r][wave] = s;
    }
    __syncthreads();
    #pragma unroll
    for (int r = 0; r < ROWS; ++r) {
        float rowsum = red[r][0] + red[r][1] + red[r][2] + red[r][3];
        float inv = 1.f / fmaxf(rowsum, EPS);
        size_t base0 = (size_t)m * N * N + (size_t)(i0 + r) * N;
        size_t base2 = base0 + 2ull * (size_t)N * N;
        for (int jt = 0; jt < N / 256; ++jt) {
            int j = jt * 256 + tid;
            float v = obuf[r][j] * inv;
            out[base0 + j] = v;
            out[base2 + j] = v;
        }
    }
}

extern "C" void kernel_launch(void* const* d_in, const int* in_sizes, int n_in,
                              void* d_out, int out_size, void* d_ws, size_t ws_size,
                              hipStream_t stream) {
    const float* z1 = (const float*)d_in[0];
    const float* z2 = (const float*)d_in[1];
    const float* W1 = (const float*)d_in[2];
    const float* b1 = (const float*)d_in[3];
    const float* W2 = (const float*)d_in[4];
    const float* b2 = (const float*)d_in[5];
    float* out = (float*)d_out;

    float* partial = (float*)d_ws;              // [2][D][SPLIT] = 512 floats
    float* p = partial + 2 * D * SPLIT;         // [2][N][D] = 128K floats (2KB offset keeps 16B alignment)

    colsum_kernel<<<2 * D * SPLIT, 256, 0, stream>>>(z1, z2, partial);
    proj_kernel<<<2 * (N / R2), 256, 0, stream>>>(z1, z2, W1, partial, p);
    pair_kernel<<<2 * (N / ROWS), 256, 0, stream>>>(p, b1, W2, b2, out);
}